// Round 3
// baseline (445.813 us; speedup 1.0000x reference)
//
#include <hip/hip_runtime.h>

// CTC loss forward, B=256 T=2000 L=100 C=36 (S=201, blank=35).
// Linear-domain alpha recursion in FP64 (range e^+-709 covers the ~300-nat
// cross-state alpha spread that flushed f32 in round 0). One wave per batch,
// 4 states per lane, async global_load_lds ring for logits rows with counted
// vmcnt (never 0). Renormalization every 32 steps by exact power-of-2
// exponent stripping (bit ops + integer exponent accumulator, no rounding).
// Per-frame softmax normalizer logZ_t factors out; S_Z = sum_t logZ_t is
// computed in a fused f32 prologue.

#define BB   256
#define TT   2000
#define LLAB 100
#define CC   36
#define BLANK 35
#define RS   32        // ring slots (power of 2)
#define ROWP 40        // floats per ring slot (36 used, padded)
#define SH2  0.5f      // shift: emission factor exp(logit - SH2)

typedef __attribute__((address_space(1))) const unsigned int* as1_u32p;
typedef __attribute__((address_space(3))) unsigned int* as3_u32p;

__device__ __forceinline__ void async_row_load(const float* g, float* lds) {
  // active lanes each load 4B: g(per-lane) -> lds_base + lane*4
  __builtin_amdgcn_global_load_lds((as1_u32p)(const void*)g,
                                   (as3_u32p)(void*)lds, 4, 0, 0);
}

#define WAITV(n) asm volatile("s_waitcnt vmcnt(" #n ")" ::: "memory")

__global__ __launch_bounds__(64) void ctc_fused(
    const float* __restrict__ logits,
    const int*   __restrict__ input_labels,
    const int*   __restrict__ input_len,
    const int*   __restrict__ label_len,
    float*       __restrict__ out)
{
  __shared__ float ring[RS + 1][ROWP];   // slot RS = dummy sink for tail issues
  const int b    = blockIdx.x;
  const int lane = threadIdx.x;
  const float* lg = logits + (size_t)b * TT * CC;
  const int ilen = input_len[b];
  const int llen = label_len[b];

  // ---------------- prologue: S_Z = sum of per-frame logsumexp ------------
  // applied frames = {0} U {1..ilen-1}
  float sz = 0.f;
  for (int t = lane; t < TT; t += 64) {
    const float4* r4 = (const float4*)(lg + t * CC);   // 144B row, 16B aligned
    float4 q[9];
#pragma unroll
    for (int i = 0; i < 9; ++i) q[i] = r4[i];
    float m = q[0].x;
#pragma unroll
    for (int i = 0; i < 9; ++i) {
      m = fmaxf(m, q[i].x); m = fmaxf(m, q[i].y);
      m = fmaxf(m, q[i].z); m = fmaxf(m, q[i].w);
    }
    float s = 0.f;
#pragma unroll
    for (int i = 0; i < 9; ++i) {
      s += __expf(q[i].x - m) + __expf(q[i].y - m)
         + __expf(q[i].z - m) + __expf(q[i].w - m);
    }
    float z = m + __logf(s);
    if (t == 0 || t < ilen) sz += z;
  }
#pragma unroll
  for (int o = 32; o; o >>= 1) sz += __shfl_xor(sz, o, 64);
  const float S_Z = sz;

  // ---------------- per-lane static state (4 states per lane) -------------
  // lane l owns states s = 4l..4l+3. Even states are blanks (no skip path),
  // so the only cross-lane value needed per step is prev-lane a3 -> one shfl.
  const int* lb = input_labels + b * LLAB;
  const int sb = 4 * lane;
  const int i0 = 2 * lane, i1 = 2 * lane + 1, im = 2 * lane - 1;
  const int lab0 = (i0 < LLAB) ? lb[i0] : 0;          // ext[4l+1]
  const int lab1 = (i1 < LLAB) ? lb[i1] : 0;          // ext[4l+3]
  const int labm = (im >= 0 && im < LLAB) ? lb[im] : 0;
  const float m0 = (sb + 0 <= 2 * LLAB) ? 1.f : 0.f;  // state-validity masks
  const float m1 = (sb + 1 <= 2 * LLAB) ? 1.f : 0.f;
  const float m2 = (sb + 2 <= 2 * LLAB) ? 1.f : 0.f;
  const float m3 = (sb + 3 <= 2 * LLAB) ? 1.f : 0.f;
  const bool skip1 = (lane >= 1) && (lab0 != BLANK) && (lab0 != labm);
  const bool skip3 = (lab1 != BLANK) && (lab1 != lab0);
  const double sk1d = skip1 ? 1.0 : 0.0;
  const double sk3d = skip3 ? 1.0 : 0.0;
  const int c1 = lab0, c3 = lab1;

  // Drain all prologue VMEM so vmcnt counts only ring loads from here on.
  asm volatile("s_waitcnt vmcnt(0)" ::: "memory");

  // issue ring prefetch for rows 0..RS-1  (outstanding = RS)
  for (int r = 0; r < RS; ++r) {
    if (lane < CC) async_row_load(lg + r * CC + lane, &ring[r][0]);
  }

  // row 0 -> alpha init (only states 0,1 nonzero; both live on lane 0)
  WAITV(31);                      // >=1 retired -> row 0 in LDS
  double a0, a1, a2 = 0.0, a3 = 0.0;
  {
    const float* rp = &ring[0][0];
    float pb = __expf(rp[BLANK] - SH2);
    float p1 = __expf(rp[c1] - SH2);
    a0 = (lane == 0) ? (double)pb : 0.0;
    a1 = (lane == 0) ? (double)p1 : 0.0;
  }
  // software-pipelined emission values for frame 1
  double pv0, pv1, pv2, pv3;
  {
    WAITV(30);                    // >=2 retired -> row 1 in LDS
    const float* rp = &ring[1][0];
    float xb = rp[BLANK], x1 = rp[c1], x3 = rp[c3];
    float pb = __expf(xb - SH2);
    float p1 = __expf(x1 - SH2);
    float p3 = __expf(x3 - SH2);
    pv0 = (double)(m0 * pb); pv2 = (double)(m2 * pb);
    pv1 = (double)(m1 * p1); pv3 = (double)(m3 * p3);
  }

  double n3 = 0.0, n3k = 0.0;     // prev-lane a3 (and skip-gated copy)
  int Eacc = 0;                   // sum of stripped power-of-2 exponents
#pragma unroll 1
  for (int t = 1; t < TT; ++t) {
    // issue prefetch for row t+RS-1 (dummy slot past the end keeps the
    // vmcnt immediate constant through the tail)
    {
      int rf = t + RS - 1;
      const float* src = lg + (size_t)((rf < TT) ? rf : (TT - 1)) * CC;
      float* dst = (rf < TT) ? &ring[rf & (RS - 1)][0] : &ring[RS][0];
      if (lane < CC) async_row_load(src + lane, dst);
    }
    // alpha update for frame t (pv*, n3, n3k prepared last iteration)
    if (t < ilen) {
      double t0 = (a0 + n3) * pv0;                 // s=4l   (blank)
      double t1 = (a1 + a0 + n3k) * pv1;           // s=4l+1 (label, skip via n3k)
      double t2 = (a2 + a1) * pv2;                 // s=4l+2 (blank)
      double t3 = (a3 + a2 + a1 * sk3d) * pv3;     // s=4l+3 (label)
      a0 = t0; a1 = t1; a2 = t2; a3 = t3;
    }
    // exact power-of-2 renormalization every 32 steps (no rounding)
    if ((t & 31) == 0) {
      double mx = fmax(fmax(a0, a1), fmax(a2, a3));
#pragma unroll
      for (int o = 32; o; o >>= 1) mx = fmax(mx, __shfl_xor(mx, o, 64));
      long long u = __double_as_longlong(mx);
      int e = (int)((u >> 52) & 0x7FF) - 1023;
      Eacc += e;
      double scale = __longlong_as_double((long long)(1023 - e) << 52); // 2^-e
      a0 *= scale; a1 *= scale; a2 *= scale; a3 *= scale;
    }
    // cross-lane neighbor for NEXT step (after renorm so scaling is uniform);
    // shfl latency overlaps the emission prep below
    n3 = __shfl_up(a3, 1, 64);
    if (lane == 0) n3 = 0.0;
    n3k = n3 * sk1d;
    // prepare emissions for frame t+1 (off the recursion's critical path)
    if (t + 1 < TT) {
      WAITV(30);                  // retired >= t+2 -> row t+1 in LDS
      const float* rp = &ring[(t + 1) & (RS - 1)][0];
      float xb = rp[BLANK], x1 = rp[c1], x3 = rp[c3];
      float pb = __expf(xb - SH2);
      float p1 = __expf(x1 - SH2);
      float p3 = __expf(x3 - SH2);
      pv0 = (double)(m0 * pb); pv2 = (double)(m2 * pb);
      pv1 = (double)(m1 * p1); pv3 = (double)(m3 * p3);
    }
  }

  // drain outstanding ring loads before workgroup teardown (late LDS writes
  // must not scribble a successor workgroup's LDS)
  asm volatile("s_waitcnt vmcnt(0)" ::: "memory");

  // ---------------- finalize ----------------------------------------------
  const int end = 2 * llen;
  const int ep  = (end > 0) ? (end - 1) : 0;
  double contrib = 0.0;
  contrib += ((sb + 0 == end) ? a0 : 0.0) + ((sb + 0 == ep) ? a0 : 0.0);
  contrib += ((sb + 1 == end) ? a1 : 0.0) + ((sb + 1 == ep) ? a1 : 0.0);
  contrib += ((sb + 2 == end) ? a2 : 0.0) + ((sb + 2 == ep) ? a2 : 0.0);
  contrib += ((sb + 3 == end) ? a3 : 0.0) + ((sb + 3 == ep) ? a3 : 0.0);
#pragma unroll
  for (int o = 32; o; o >>= 1) contrib += __shfl_xor(contrib, o, 64);

  if (lane == 0) {
    // log(contrib) via exponent/mantissa split (f32 log on mantissa in [1,2))
    long long u = __double_as_longlong(contrib);
    int e = (int)((u >> 52) & 0x7FF) - 1023;
    double mant = __longlong_as_double(
        (u & 0xFFFFFFFFFFFFFULL) | 0x3FF0000000000000ULL);
    double lc = (double)e * 0.6931471805599453 + (double)__logf((float)mant);
    int tl = (ilen < TT) ? ilen : TT;
    int napp = 1 + ((tl > 1) ? (tl - 1) : 0);   // emissions applied
    double loss = -(lc + (double)Eacc * 0.6931471805599453
                    + (double)SH2 * (double)napp - (double)S_Z);
    out[b] = (float)loss;
  }
}

extern "C" void kernel_launch(void* const* d_in, const int* in_sizes, int n_in,
                              void* d_out, int out_size, void* d_ws, size_t ws_size,
                              hipStream_t stream) {
  const float* logits = (const float*)d_in[0];
  const int* labels   = (const int*)d_in[1];
  const int* ilen     = (const int*)d_in[2];
  const int* llen     = (const int*)d_in[3];
  float* out          = (float*)d_out;
  (void)in_sizes; (void)n_in; (void)out_size; (void)d_ws; (void)ws_size;
  hipLaunchKernelGGL(ctc_fused, dim3(BB), dim3(64), 0, stream,
                     logits, labels, ilen, llen, out);
}

// Round 4
// 231.347 us; speedup vs baseline: 1.9270x; 1.9270x over previous
//
#include <hip/hip_runtime.h>

// CTC loss forward, B=256 T=2000 L=100 C=36 (S=201, blank=35).
// FP64 linear-domain alpha recursion, one wave per batch, 4 states per lane.
// Round-4 structure: NO LDS/DS ops in the serial loop --
//   * neighbor exchange via DPP wave_shr:1 (VALU latency, not DS),
//   * emissions loaded straight to VGPRs (8-deep static register ring,
//     3 scalar columns per lane per step; compiler-managed vmcnt),
//   * renorm every 32 steps via DPP int-max reduce on f64 hi-words +
//     exact power-of-2 exponent stripping (integer accumulator).
// Per-frame softmax normalizer factors out; S_Z computed in f32 prologue.

#define BB    256
#define TT    2000
#define LLAB  100
#define CC    36
#define BLANK 35
#define LN2   0.6931471805599453

static __device__ __forceinline__ int imax(int a, int b) { return a > b ? a : b; }

// lane i gets lane i-1's value; lane 0 gets 0.  (DPP wave_shr:1, zero-fill)
static __device__ __forceinline__ double dpp_up1(double x) {
  long long v = __double_as_longlong(x);
  int lo = (int)(unsigned int)(v & 0xFFFFFFFFLL);
  int hi = (int)(v >> 32);
  int slo = __builtin_amdgcn_update_dpp(0, lo, 0x138, 0xF, 0xF, true);
  int shi = __builtin_amdgcn_update_dpp(0, hi, 0x138, 0xF, 0xF, true);
  long long r = ((long long)shi << 32) | (long long)(unsigned int)slo;
  return __longlong_as_double(r);
}

// wave-wide int max via DPP (row_shr 1/2/4/8, bcast15, bcast31), result
// broadcast from lane 63 as a uniform value.
static __device__ __forceinline__ int wave_imax(int x) {
  x = imax(x, __builtin_amdgcn_update_dpp(x, x, 0x111, 0xF, 0xF, false));
  x = imax(x, __builtin_amdgcn_update_dpp(x, x, 0x112, 0xF, 0xF, false));
  x = imax(x, __builtin_amdgcn_update_dpp(x, x, 0x114, 0xF, 0xF, false));
  x = imax(x, __builtin_amdgcn_update_dpp(x, x, 0x118, 0xF, 0xF, false));
  x = imax(x, __builtin_amdgcn_update_dpp(x, x, 0x142, 0xA, 0xF, false));
  x = imax(x, __builtin_amdgcn_update_dpp(x, x, 0x143, 0xC, 0xF, false));
  return __builtin_amdgcn_readlane(x, 63);
}

__global__ __launch_bounds__(64) void ctc_fused(
    const float* __restrict__ logits,
    const int*   __restrict__ input_labels,
    const int*   __restrict__ input_len,
    const int*   __restrict__ label_len,
    float*       __restrict__ out)
{
  const int b    = blockIdx.x;
  const int lane = threadIdx.x;
  const float* lg = logits + (size_t)b * TT * CC;
  const int ilen = input_len[b];
  const int llen = label_len[b];

  // ---------------- prologue: S_Z = sum of per-frame logsumexp ------------
  float sz = 0.f;
  for (int t = lane; t < TT; t += 64) {
    const float4* r4 = (const float4*)(lg + t * CC);   // 144B row, 16B aligned
    float4 q[9];
#pragma unroll
    for (int i = 0; i < 9; ++i) q[i] = r4[i];
    float m = q[0].x;
#pragma unroll
    for (int i = 0; i < 9; ++i) {
      m = fmaxf(m, q[i].x); m = fmaxf(m, q[i].y);
      m = fmaxf(m, q[i].z); m = fmaxf(m, q[i].w);
    }
    float s = 0.f;
#pragma unroll
    for (int i = 0; i < 9; ++i) {
      s += __expf(q[i].x - m) + __expf(q[i].y - m)
         + __expf(q[i].z - m) + __expf(q[i].w - m);
    }
    float z = m + __logf(s);
    if (t == 0 || t < ilen) sz += z;
  }
#pragma unroll
  for (int o = 32; o; o >>= 1) sz += __shfl_xor(sz, o, 64);
  const float S_Z = sz;

  // ---------------- per-lane static state (states 4l..4l+3) ---------------
  const int* lb = input_labels + b * LLAB;
  const int i0 = 2 * lane, i1 = 2 * lane + 1, im = 2 * lane - 1;
  const int c1 = (i0 < LLAB) ? lb[i0] : 0;            // ext[4l+1]
  const int c3 = (i1 < LLAB) ? lb[i1] : 0;            // ext[4l+3]
  const int cm = (im >= 0 && im < LLAB) ? lb[im] : 0;
  const bool skip1 = (lane >= 1) && (c1 != BLANK) && (c1 != cm);
  const bool skip3 = (c3 != BLANK) && (c3 != c1);
  // byte offsets of the 3 needed columns within a row
  const int ob = BLANK * 4, o1 = c1 * 4, o3 = c3 * 4;

  // ---------------- t=0 init ----------------------------------------------
  double a0 = 0.0, a1 = 0.0, a2 = 0.0, a3 = 0.0;
  {
    const char* r0 = (const char*)lg;
    float eb = *(const float*)(r0 + ob);
    float e1 = *(const float*)(r0 + o1);
    if (lane == 0) { a0 = (double)__expf(eb); a1 = (double)__expf(e1); }
  }

  // ---------------- 8-deep register ring: rows 1..8 -----------------------
  float fb[8], f1[8], f3[8];
#pragma unroll
  for (int r = 1; r <= 8; ++r) {
    const char* rp = (const char*)(lg + r * CC);
    fb[r & 7] = *(const float*)(rp + ob);
    f1[r & 7] = *(const float*)(rp + o1);
    f3[r & 7] = *(const float*)(rp + o3);
  }
  // emissions for frame 1 (slot 1)
  double pv0, pv1, pv3;
  {
    float pb = __expf(fb[1]);
    pv0 = (double)pb;
    pv1 = (double)__expf(f1[1]);
    pv3 = (double)__expf(f3[1]);
  }

  double n3 = 0.0, n3k = 0.0;   // prev-lane a3 (and skip1-gated copy)
  int Eacc = 0;                 // sum of stripped power-of-2 exponents
  const float* pfetch = lg + 9 * CC;   // first row issued inside the loop

#define STEP_BODY(J, T, DO_FETCH)                                          \
  {                                                                        \
    if (DO_FETCH) {                                                        \
      const char* rp_ = (const char*)pfetch;                               \
      fb[((J) + 1) & 7] = *(const float*)(rp_ + ob);                       \
      f1[((J) + 1) & 7] = *(const float*)(rp_ + o1);                       \
      f3[((J) + 1) & 7] = *(const float*)(rp_ + o3);                       \
    }                                                                      \
    pfetch += CC;                                                          \
    if ((T) < ilen) {                                                      \
      double g3 = skip3 ? a1 : 0.0;                                        \
      double u0 = (a0 + n3) * pv0;                                         \
      double u1 = (a1 + a0 + n3k) * pv1;                                   \
      double u2 = (a2 + a1) * pv0;        /* pv2 == pv0 (blank) */         \
      double u3 = (a3 + a2 + g3) * pv3;                                    \
      a0 = u0; a1 = u1; a2 = u2; a3 = u3;                                  \
    }                                                                      \
    n3  = dpp_up1(a3);                                                     \
    n3k = skip1 ? n3 : 0.0;                                                \
    {                                                                      \
      float pb_ = __expf(fb[((J) + 2) & 7]);                               \
      pv0 = (double)pb_;                                                   \
      pv1 = (double)__expf(f1[((J) + 2) & 7]);                             \
      pv3 = (double)__expf(f3[((J) + 2) & 7]);                             \
    }                                                                      \
  }

#define RENORM_CHECK(TB)                                                   \
  if (((TB) & 31) == 25) {                                                 \
    int h0 = (int)(__double_as_longlong(a0) >> 32);                        \
    int h1 = (int)(__double_as_longlong(a1) >> 32);                        \
    int h2 = (int)(__double_as_longlong(a2) >> 32);                        \
    int h3 = (int)(__double_as_longlong(a3) >> 32);                        \
    int ebias = wave_imax(imax(imax(h0, h1), imax(h2, h3))) >> 20;         \
    Eacc += ebias - 1023;                                                  \
    double scale = __longlong_as_double((long long)(2046 - ebias) << 52);  \
    a0 *= scale; a1 *= scale; a2 *= scale; a3 *= scale;                    \
    n3 *= scale; n3k *= scale;                                             \
  }

  // main loop, bodies t=1..1984 (prefetch rows 9..1992, all in-bounds)
#pragma unroll 1
  for (int tb = 1; tb <= 1977; tb += 8) {
#pragma unroll
    for (int j = 0; j < 8; ++j) { const int t = tb + j; STEP_BODY(j, t, true) }
    RENORM_CHECK(tb)
  }
  // guarded iteration: bodies t=1985..1992 (prefetch rows 1993..1999 only)
  {
    const int tb = 1985;
#pragma unroll
    for (int j = 0; j < 8; ++j) {
      const int t = tb + j;
      STEP_BODY(j, t, (t + 8 < TT))
    }
    RENORM_CHECK(tb)
  }
  // tail, bodies t=1993..1999 (no prefetch; slots already hold rows 1994..1999)
#pragma unroll
  for (int k = 0; k < 7; ++k) {
    const int t = 1993 + k;
    if (t < ilen) {
      double g3 = skip3 ? a1 : 0.0;
      double u0 = (a0 + n3) * pv0;
      double u1 = (a1 + a0 + n3k) * pv1;
      double u2 = (a2 + a1) * pv0;
      double u3 = (a3 + a2 + g3) * pv3;
      a0 = u0; a1 = u1; a2 = u2; a3 = u3;
    }
    n3  = dpp_up1(a3);
    n3k = skip1 ? n3 : 0.0;
    if (t + 1 < TT) {
      float pb = __expf(fb[(t + 1) & 7]);
      pv0 = (double)pb;
      pv1 = (double)__expf(f1[(t + 1) & 7]);
      pv3 = (double)__expf(f3[(t + 1) & 7]);
    }
  }

  // ---------------- finalize ----------------------------------------------
  const int sb  = 4 * lane;
  const int end = 2 * llen;
  const int ep  = (end > 0) ? (end - 1) : 0;
  double contrib = 0.0;
  contrib += ((sb + 0 == end) ? a0 : 0.0) + ((sb + 0 == ep) ? a0 : 0.0);
  contrib += ((sb + 1 == end) ? a1 : 0.0) + ((sb + 1 == ep) ? a1 : 0.0);
  contrib += ((sb + 2 == end) ? a2 : 0.0) + ((sb + 2 == ep) ? a2 : 0.0);
  contrib += ((sb + 3 == end) ? a3 : 0.0) + ((sb + 3 == ep) ? a3 : 0.0);
#pragma unroll
  for (int o = 32; o; o >>= 1) contrib += __shfl_xor(contrib, o, 64);

  if (lane == 0) {
    long long u = __double_as_longlong(contrib);
    int e = (int)((u >> 52) & 0x7FF) - 1023;
    double mant = __longlong_as_double(
        (u & 0xFFFFFFFFFFFFFULL) | 0x3FF0000000000000ULL);
    double lc = (double)e * LN2 + (double)__logf((float)mant);
    double loss = -(lc + (double)Eacc * LN2 - (double)S_Z);
    out[b] = (float)loss;
  }
#undef STEP_BODY
#undef RENORM_CHECK
}

extern "C" void kernel_launch(void* const* d_in, const int* in_sizes, int n_in,
                              void* d_out, int out_size, void* d_ws, size_t ws_size,
                              hipStream_t stream) {
  const float* logits = (const float*)d_in[0];
  const int* labels   = (const int*)d_in[1];
  const int* ilen     = (const int*)d_in[2];
  const int* llen     = (const int*)d_in[3];
  float* out          = (float*)d_out;
  (void)in_sizes; (void)n_in; (void)out_size; (void)d_ws; (void)ws_size;
  hipLaunchKernelGGL(ctc_fused, dim3(BB), dim3(64), 0, stream,
                     logits, labels, ilen, llen, out);
}